// Round 1
// baseline (17487.643 us; speedup 1.0000x reference)
//
#include <hip/hip_runtime.h>
#include <cstdint>
#include <cstddef>

// MessagePassing (SCNN-style): 4 sequential directional scans.
// B=16 C=128 H=72 W=200 K=9 pad=4, fp32 in/out.
//
// Round-0 design notes:
//  - fp32 vector-ALU compute (no fp32 MFMA on CDNA4); correctness-first.
//  - per pass: ONE persistent kernel, 256 blocks = (b, co_oct). Cross-block
//    row dependency synced with per-(b,row) agent-scope atomic counters
//    (16 producers per row). Grid 256 @ 53KB LDS -> >=3 blocks/CU capacity,
//    co-residency guaranteed.
//  - W-scans run on an h<->w transposed copy so the conv axis is contiguous.
//  - flags in d_ws (memset each launch); transpose scratch = d_ws tail if it
//    fits, else d_in[0] (x is dead after initial copy; harness restores it).

#define B_ 16
#define C_ 128
#define H_ 72
#define W_ 200
#define KW 9
#define NTOT (B_ * C_ * H_ * W_)  // 29,491,200 elements

// ---------------- copy x -> out ----------------
__global__ void copy_f4(const float4* __restrict__ src, float4* __restrict__ dst, int n4) {
  int i = blockIdx.x * blockDim.x + threadIdx.x;
  const int stride = gridDim.x * blockDim.x;
  for (; i < n4; i += stride) dst[i] = src[i];
}

// ---------------- transpose last two dims: src[bc][SH][SW] -> dst[bc][SW][SH] ----------------
template <int SH, int SW>
__global__ void transpose_hw(const float* __restrict__ src, float* __restrict__ dst) {
  __shared__ float t[32][33];
  const size_t base = (size_t)blockIdx.z * SH * SW;
  const int x = blockIdx.x * 32 + threadIdx.x;  // SW coord
#pragma unroll
  for (int j = 0; j < 4; ++j) {
    const int y = blockIdx.y * 32 + threadIdx.y + j * 8;  // SH coord
    if (y < SH && x < SW) t[threadIdx.y + j * 8][threadIdx.x] = src[base + (size_t)y * SW + x];
  }
  __syncthreads();
  const int x2 = blockIdx.y * 32 + threadIdx.x;  // SH coord, contiguous in dst
#pragma unroll
  for (int j = 0; j < 4; ++j) {
    const int y2 = blockIdx.x * 32 + threadIdx.y + j * 8;  // SW coord = dst row
    if (y2 < SW && x2 < SH) dst[base + (size_t)y2 * SH + x2] = t[threadIdx.x][threadIdx.y + j * 8];
  }
}

// ---------------- directional scan pass ----------------
// data[b][c][RDIM][WDIM]; scan over RDIM rows, conv (K=9, pad 4) over contiguous WDIM.
// out[r] = out[r] + relu(sum_{ci,k} out[r-dir][ci, w+k-4] * wgt[co,ci,k])
// 256 blocks: block = (b, co_oct of 8 channels). 4 waves; wave handles co0=oct*8+2*wave, co1=co0+1
// (wave-uniform -> scalar weight loads). Lane computes 4 consecutive w (lanes < WDIM/4 active).
// Prev row staged to LDS in two 64-ci halves. Per-(b,row) flag counter: 16 producers.
template <int RDIM, int WDIM>
__global__ __launch_bounds__(256, 1) void pass_kernel(float* __restrict__ data,
                                                      const float* __restrict__ wgt,
                                                      unsigned* flags, const int dir) {
  constexpr int S = WDIM + 8;    // LDS row stride (4-halo each side)
  constexpr int NL = WDIM / 4;   // active lanes (50 or 18)
  constexpr int NF4 = WDIM / 4;  // float4 per staged row
  __shared__ float P[64 * S];    // 53,248 B (WDIM=200) / 20,480 B (WDIM=72)

  const int tid = threadIdx.x;
  const int blk = blockIdx.x;
  // XCD-swizzle heuristic: same-b blocks share blk%8 -> likely same XCD (perf only).
  const int b = (blk & 7) + ((blk >> 7) << 3);
  const int co_oct = (blk >> 3) & 15;
  const int wave = tid >> 6;
  const int lane = tid & 63;
  const int lane_c = lane < NL ? lane : NL - 1;
  const int wl = 4 * lane_c;
  const bool active = lane < NL;
  const int co0 = __builtin_amdgcn_readfirstlane(co_oct * 8 + wave * 2);
  const int co1 = co0 + 1;

  // zero LDS halos once (never overwritten by staging)
  if (tid < 64) {
#pragma unroll
    for (int m = 0; m < 4; ++m) {
      P[tid * S + m] = 0.f;
      P[tid * S + WDIM + 4 + m] = 0.f;
    }
  }

  const size_t bbase = (size_t)b * C_ * RDIM * WDIM;

  for (int s = 1; s < RDIM; ++s) {
    const int r = (dir > 0) ? s : (RDIM - 1 - s);
    const int rp = r - dir;  // producer row

    if (s > 1) {
      if (tid == 0) {
        unsigned* f = &flags[b * RDIM + rp];
        while (__hip_atomic_load(f, __ATOMIC_RELAXED, __HIP_MEMORY_SCOPE_AGENT) < 16u)
          __builtin_amdgcn_s_sleep(4);
        (void)__hip_atomic_load(f, __ATOMIC_ACQUIRE, __HIP_MEMORY_SCOPE_AGENT);
      }
      // waves join at the __syncthreads at the top of the half-loop below
    }

    float a0[4] = {0.f, 0.f, 0.f, 0.f};
    float a1[4] = {0.f, 0.f, 0.f, 0.f};

#pragma unroll
    for (int half = 0; half < 2; ++half) {
      __syncthreads();  // orders: flag-wait / previous compute reads of P / halo init
      // stage ci in [half*64, half*64+64) of row rp
      for (int idx = tid; idx < 64 * NF4; idx += 256) {
        const int i = idx / NF4;
        const int q = idx - i * NF4;
        const float4 v = *(const float4*)(data + bbase +
                                          ((size_t)(half * 64 + i) * RDIM + rp) * WDIM + 4 * q);
        *(float4*)(&P[i * S + 4 + 4 * q]) = v;
      }
      __syncthreads();

      const float* wb0 = wgt + ((size_t)co0 * C_ + half * 64) * KW;
      const float* wb1 = wgt + ((size_t)co1 * C_ + half * 64) * KW;
      for (int ci = 0; ci < 64; ++ci) {
        const float4 f0 = *(const float4*)(&P[ci * S + wl]);
        const float4 f1 = *(const float4*)(&P[ci * S + wl + 4]);
        const float4 f2 = *(const float4*)(&P[ci * S + wl + 8]);
        const float rr[12] = {f0.x, f0.y, f0.z, f0.w, f1.x, f1.y,
                              f1.z, f1.w, f2.x, f2.y, f2.z, f2.w};
        const float* w0 = wb0 + ci * KW;
        const float* w1 = wb1 + ci * KW;
#pragma unroll
        for (int k = 0; k < KW; ++k) {
          const float wk0 = w0[k];
          const float wk1 = w1[k];
          a0[0] = fmaf(wk0, rr[k + 0], a0[0]);
          a0[1] = fmaf(wk0, rr[k + 1], a0[1]);
          a0[2] = fmaf(wk0, rr[k + 2], a0[2]);
          a0[3] = fmaf(wk0, rr[k + 3], a0[3]);
          a1[0] = fmaf(wk1, rr[k + 0], a1[0]);
          a1[1] = fmaf(wk1, rr[k + 1], a1[1]);
          a1[2] = fmaf(wk1, rr[k + 2], a1[2]);
          a1[3] = fmaf(wk1, rr[k + 3], a1[3]);
        }
      }
    }

    if (active) {
      float* p0 = data + bbase + ((size_t)co0 * RDIM + r) * WDIM + wl;
      float4 c0 = *(float4*)p0;
      c0.x += fmaxf(a0[0], 0.f);
      c0.y += fmaxf(a0[1], 0.f);
      c0.z += fmaxf(a0[2], 0.f);
      c0.w += fmaxf(a0[3], 0.f);
      *(float4*)p0 = c0;
      float* p1 = data + bbase + ((size_t)co1 * RDIM + r) * WDIM + wl;
      float4 c1 = *(float4*)p1;
      c1.x += fmaxf(a1[0], 0.f);
      c1.y += fmaxf(a1[1], 0.f);
      c1.z += fmaxf(a1[2], 0.f);
      c1.w += fmaxf(a1[3], 0.f);
      *(float4*)p1 = c1;
    }
    __syncthreads();  // compiler emits s_waitcnt vmcnt(0) before s_barrier: stores drained
    if (tid == 0)
      __hip_atomic_fetch_add(&flags[b * RDIM + r], 1u, __ATOMIC_RELEASE,
                             __HIP_MEMORY_SCOPE_AGENT);
  }
}

extern "C" void kernel_launch(void* const* d_in, const int* in_sizes, int n_in, void* d_out,
                              int out_size, void* d_ws, size_t ws_size, hipStream_t stream) {
  const float* x = (const float*)d_in[0];
  const float* w_down = (const float*)d_in[1];
  const float* w_up = (const float*)d_in[2];
  const float* w_right = (const float*)d_in[3];
  const float* w_left = (const float*)d_in[4];
  float* out = (float*)d_out;

  // flag layout in d_ws (first 64 KB, memset to 0 each launch)
  unsigned* flags = (unsigned*)d_ws;
  unsigned* f_down = flags;                 // 16*72
  unsigned* f_up = f_down + B_ * H_;        // 16*72
  unsigned* f_right = f_up + B_ * H_;       // 16*200
  unsigned* f_left = f_right + B_ * W_;     // 16*200
  hipMemsetAsync(d_ws, 0, 65536, stream);

  // transpose scratch: d_ws tail if it fits, else reuse x's buffer (dead after copy)
  const size_t tbytes = (size_t)NTOT * sizeof(float);
  float* T;
  if (ws_size >= 65536 + tbytes)
    T = (float*)((char*)d_ws + 65536);
  else
    T = (float*)d_in[0];

  // 1) out = x
  copy_f4<<<1024, 256, 0, stream>>>((const float4*)x, (float4*)out, NTOT / 4);

  // 2) down (scan h forward), 3) up (scan h backward) -- conv over contiguous w
  pass_kernel<H_, W_><<<256, 256, 0, stream>>>(out, w_down, f_down, +1);
  pass_kernel<H_, W_><<<256, 256, 0, stream>>>(out, w_up, f_up, -1);

  // 4) transpose [b,c,h,w] -> [b,c,w,h]
  {
    dim3 g((W_ + 31) / 32, (H_ + 31) / 32, B_ * C_);
    transpose_hw<H_, W_><<<g, dim3(32, 8), 0, stream>>>(out, T);
  }

  // 5) right (scan w forward), 6) left (scan w backward) -- conv over contiguous h
  pass_kernel<W_, H_><<<256, 256, 0, stream>>>(T, w_right, f_right, +1);
  pass_kernel<W_, H_><<<256, 256, 0, stream>>>(T, w_left, f_left, -1);

  // 7) transpose back [b,c,w,h] -> [b,c,h,w]
  {
    dim3 g((H_ + 31) / 32, (W_ + 31) / 32, B_ * C_);
    transpose_hw<W_, H_><<<g, dim3(32, 8), 0, stream>>>(T, out);
  }
}

// Round 2
// 16596.751 us; speedup vs baseline: 1.0537x; 1.0537x over previous
//
#include <hip/hip_runtime.h>
#include <cstdint>
#include <cstddef>

// MessagePassing (SCNN-style): 4 sequential directional scans.
// B=16 C=128 H=72 W=200 K=9 pad=4, fp32 in/out.
//
// Round-1 changes vs round-0 (17.5ms, OccupancyPercent 12.2 = 1 wave/SIMD):
//  - 512-thread blocks (8 waves) -> 2 waves/SIMD latency hiding.
//  - W-pass: 3-way ci-split across lane groups (18 lanes each reduce 43 ci),
//    full 128-ci prev row in LDS (40KB), ds_bpermute combine. Lane util 28->84%.
//  - H-pass: wave = 1 co (50 lanes x 4 pos), 2x64-ci chunks (53KB LDS),
//    wave-uniform scalar weight loads.
//  - Sync skeleton unchanged (proven correct round 0): per-(b,row) agent-scope
//    counters, 16 producers; grid 256 co-resident (4-block/CU thread capacity).

#define B_ 16
#define C_ 128
#define H_ 72
#define W_ 200
#define KW 9
#define NTOT (B_ * C_ * H_ * W_)  // 29,491,200 elements

// ---------------- copy x -> out ----------------
__global__ void copy_f4(const float4* __restrict__ src, float4* __restrict__ dst, int n4) {
  int i = blockIdx.x * blockDim.x + threadIdx.x;
  const int stride = gridDim.x * blockDim.x;
  for (; i < n4; i += stride) dst[i] = src[i];
}

// ---------------- transpose last two dims: src[bc][SH][SW] -> dst[bc][SW][SH] ----------------
template <int SH, int SW>
__global__ void transpose_hw(const float* __restrict__ src, float* __restrict__ dst) {
  __shared__ float t[32][33];
  const size_t base = (size_t)blockIdx.z * SH * SW;
  const int x = blockIdx.x * 32 + threadIdx.x;  // SW coord
#pragma unroll
  for (int j = 0; j < 4; ++j) {
    const int y = blockIdx.y * 32 + threadIdx.y + j * 8;  // SH coord
    if (y < SH && x < SW) t[threadIdx.y + j * 8][threadIdx.x] = src[base + (size_t)y * SW + x];
  }
  __syncthreads();
  const int x2 = blockIdx.y * 32 + threadIdx.x;  // SH coord, contiguous in dst
#pragma unroll
  for (int j = 0; j < 4; ++j) {
    const int y2 = blockIdx.x * 32 + threadIdx.y + j * 8;  // SW coord = dst row
    if (y2 < SW && x2 < SH) dst[base + (size_t)y2 * SH + x2] = t[threadIdx.x][threadIdx.y + j * 8];
  }
}

// ---------------- directional scan pass ----------------
// data[b][c][RDIM][WDIM]; scan RDIM rows; conv (K=9, pad 4) over contiguous WDIM.
// 256 blocks = (b, co_oct). 512 threads = 8 waves; wave -> co = oct*8 + wave.
// NSPLIT==1 (H-pass): lane -> 4 contiguous pos (lanes < WDIM/4 active), ci staged
//   in NCHUNK chunks of C_/NCHUNK rows; weights wave-uniform (scalar loads).
// NSPLIT==3 (W-pass): lane groups {0..17,18..35,36..53} reduce ci slices
//   {0..42,43..85,86..127}; full 128-ci row in LDS; per-group broadcast weight
//   loads (L1-resident); 3-way ds_bpermute combine; lanes 0..17 write.
template <int RDIM, int WDIM, int NCHUNK, int NSPLIT>
__global__ __launch_bounds__(512, 1) void pass_kernel(float* __restrict__ data,
                                                      const float* __restrict__ wgt,
                                                      unsigned* flags, const int dir) {
  constexpr int S = WDIM + 8;        // LDS row stride (4-halo each side)
  constexpr int CROWS = C_ / NCHUNK; // ci rows resident per staged chunk
  constexpr int NL = WDIM / 4;       // writer lanes (pos groups of 4)
  constexpr int NF4 = WDIM / 4;      // float4 per staged row
  __shared__ float P[CROWS * S];     // W: 128*80*4=40,960B  H: 64*208*4=53,248B

  const int tid = threadIdx.x;
  const int blk = blockIdx.x;
  const int b = (blk & 7) + ((blk >> 7) << 3);  // XCD-swizzle heuristic (perf only)
  const int co_oct = (blk >> 3) & 15;
  const int lane = tid & 63;
  const int co = __builtin_amdgcn_readfirstlane(co_oct * 8 + (tid >> 6));

  int g = 0, pl = lane;
  if (NSPLIT == 3) {
    g = lane / 18;
    if (g > 2) g = 2;
    pl = lane - g * 18;
  }
  if (pl > NL - 1) pl = NL - 1;
  const int wl = 4 * pl;  // dword offset of first output pos within padded row

  // zero LDS halos once (staging never writes them)
  if (tid < CROWS) {
#pragma unroll
    for (int m = 0; m < 4; ++m) {
      P[tid * S + m] = 0.f;
      P[tid * S + WDIM + 4 + m] = 0.f;
    }
  }

  const size_t bbase = (size_t)b * C_ * RDIM * WDIM;

  for (int s = 1; s < RDIM; ++s) {
    const int r = (dir > 0) ? s : (RDIM - 1 - s);
    const int rp = r - dir;  // producer row

    if (s > 1 && tid == 0) {
      unsigned* f = &flags[b * RDIM + rp];
      while (__hip_atomic_load(f, __ATOMIC_RELAXED, __HIP_MEMORY_SCOPE_AGENT) < 16u)
        __builtin_amdgcn_s_sleep(1);
      (void)__hip_atomic_load(f, __ATOMIC_ACQUIRE, __HIP_MEMORY_SCOPE_AGENT);
    }

    float acc[4] = {0.f, 0.f, 0.f, 0.f};

#pragma unroll
    for (int ch = 0; ch < NCHUNK; ++ch) {
      __syncthreads();  // joins spin; protects P from prior compute/halo-init
      // stage ci rows [ch*CROWS, ch*CROWS+CROWS) of producer row rp
      for (int idx = tid; idx < CROWS * NF4; idx += 512) {
        const int i = idx / NF4;
        const int q = idx - i * NF4;
        const float4 v = *(const float4*)(data + bbase +
                                          ((size_t)(ch * CROWS + i) * RDIM + rp) * WDIM + 4 * q);
        *(float4*)(&P[i * S + 4 + 4 * q]) = v;
      }
      __syncthreads();

      if (NSPLIT == 3) {
        const float* wbase = wgt + (size_t)co * C_ * KW;
#pragma unroll 2
        for (int i = 0; i < 43; ++i) {
          const int ci = g * 43 + i;
          if (ci < C_) {
            float w9[9];
            __builtin_memcpy(&w9[0], wbase + ci * KW, 16);
            __builtin_memcpy(&w9[4], wbase + ci * KW + 4, 16);
            w9[8] = wbase[ci * KW + 8];
            const float4 f0 = *(const float4*)(&P[ci * S + wl]);
            const float4 f1 = *(const float4*)(&P[ci * S + wl + 4]);
            const float4 f2 = *(const float4*)(&P[ci * S + wl + 8]);
            const float rr[12] = {f0.x, f0.y, f0.z, f0.w, f1.x, f1.y,
                                  f1.z, f1.w, f2.x, f2.y, f2.z, f2.w};
#pragma unroll
            for (int k = 0; k < KW; ++k) {
              const float wk = w9[k];
              acc[0] = fmaf(wk, rr[k + 0], acc[0]);
              acc[1] = fmaf(wk, rr[k + 1], acc[1]);
              acc[2] = fmaf(wk, rr[k + 2], acc[2]);
              acc[3] = fmaf(wk, rr[k + 3], acc[3]);
            }
          }
        }
      } else {
        const float* wbase = wgt + ((size_t)co * C_ + ch * CROWS) * KW;
#pragma unroll 2
        for (int i = 0; i < CROWS; ++i) {
          const float* w = wbase + i * KW;  // wave-uniform -> s_load
          const float4 f0 = *(const float4*)(&P[i * S + wl]);
          const float4 f1 = *(const float4*)(&P[i * S + wl + 4]);
          const float4 f2 = *(const float4*)(&P[i * S + wl + 8]);
          const float rr[12] = {f0.x, f0.y, f0.z, f0.w, f1.x, f1.y,
                                f1.z, f1.w, f2.x, f2.y, f2.z, f2.w};
#pragma unroll
          for (int k = 0; k < KW; ++k) {
            const float wk = w[k];
            acc[0] = fmaf(wk, rr[k + 0], acc[0]);
            acc[1] = fmaf(wk, rr[k + 1], acc[1]);
            acc[2] = fmaf(wk, rr[k + 2], acc[2]);
            acc[3] = fmaf(wk, rr[k + 3], acc[3]);
          }
        }
      }
    }

    if (NSPLIT == 3) {
      // combine the 3 ci-slice partials into lanes 0..17 (all 64 lanes active)
#pragma unroll
      for (int m = 0; m < 4; ++m) {
        const int a = __float_as_int(acc[m]);
        const int v1 = __builtin_amdgcn_ds_bpermute((((lane + 18) & 63) << 2), a);
        const int v2 = __builtin_amdgcn_ds_bpermute((((lane + 36) & 63) << 2), a);
        acc[m] += __int_as_float(v1) + __int_as_float(v2);
      }
    }

    if (lane < NL && (NSPLIT == 1 || lane < 18)) {
      float* p = data + bbase + ((size_t)co * RDIM + r) * WDIM + wl;
      float4 cc = *(float4*)p;
      cc.x += fmaxf(acc[0], 0.f);
      cc.y += fmaxf(acc[1], 0.f);
      cc.z += fmaxf(acc[2], 0.f);
      cc.w += fmaxf(acc[3], 0.f);
      *(float4*)p = cc;
    }
    __syncthreads();  // vmcnt(0) drain before barrier -> stores complete
    if (tid == 0)
      __hip_atomic_fetch_add(&flags[b * RDIM + r], 1u, __ATOMIC_RELEASE,
                             __HIP_MEMORY_SCOPE_AGENT);
  }
}

extern "C" void kernel_launch(void* const* d_in, const int* in_sizes, int n_in, void* d_out,
                              int out_size, void* d_ws, size_t ws_size, hipStream_t stream) {
  const float* x = (const float*)d_in[0];
  const float* w_down = (const float*)d_in[1];
  const float* w_up = (const float*)d_in[2];
  const float* w_right = (const float*)d_in[3];
  const float* w_left = (const float*)d_in[4];
  float* out = (float*)d_out;

  // flag layout in d_ws (first 64 KB, memset to 0 each launch)
  unsigned* flags = (unsigned*)d_ws;
  unsigned* f_down = flags;              // 16*72
  unsigned* f_up = f_down + B_ * H_;     // 16*72
  unsigned* f_right = f_up + B_ * H_;    // 16*200
  unsigned* f_left = f_right + B_ * W_;  // 16*200
  hipMemsetAsync(d_ws, 0, 65536, stream);

  // transpose scratch: d_ws tail if it fits, else reuse x's buffer (dead after copy)
  const size_t tbytes = (size_t)NTOT * sizeof(float);
  float* T;
  if (ws_size >= 65536 + tbytes)
    T = (float*)((char*)d_ws + 65536);
  else
    T = (float*)d_in[0];

  // 1) out = x
  copy_f4<<<1024, 256, 0, stream>>>((const float4*)x, (float4*)out, NTOT / 4);

  // 2) down (scan h fwd), 3) up (scan h bwd) -- conv over contiguous w (H-pass: NCHUNK=2, NSPLIT=1)
  pass_kernel<H_, W_, 2, 1><<<256, 512, 0, stream>>>(out, w_down, f_down, +1);
  pass_kernel<H_, W_, 2, 1><<<256, 512, 0, stream>>>(out, w_up, f_up, -1);

  // 4) transpose [b,c,h,w] -> [b,c,w,h]
  {
    dim3 g((W_ + 31) / 32, (H_ + 31) / 32, B_ * C_);
    transpose_hw<H_, W_><<<g, dim3(32, 8), 0, stream>>>(out, T);
  }

  // 5) right (scan w fwd), 6) left (scan w bwd) -- conv over contiguous h (W-pass: NCHUNK=1, NSPLIT=3)
  pass_kernel<W_, H_, 1, 3><<<256, 512, 0, stream>>>(T, w_right, f_right, +1);
  pass_kernel<W_, H_, 1, 3><<<256, 512, 0, stream>>>(T, w_left, f_left, -1);

  // 7) transpose back [b,c,w,h] -> [b,c,h,w]
  {
    dim3 g((H_ + 31) / 32, (W_ + 31) / 32, B_ * C_);
    transpose_hw<W_, H_><<<g, dim3(32, 8), 0, stream>>>(T, out);
  }
}

// Round 3
// 7937.623 us; speedup vs baseline: 2.2031x; 2.0909x over previous
//
#include <hip/hip_runtime.h>
#include <cstdint>
#include <cstddef>

// MessagePassing (SCNN-style): 4 sequential directional scans.
// B=16 C=128 H=72 W=200 K=9 pad=4, fp32 in/out.
//
// Round-2: MFMA engine (split-fp16, 3-term: Whi*Ahi + Whi*Alo + Wlo*Ahi,
// rel err ~2^-22 -> absmax should match fp32 baseline 0.25).
//  - block = (b, 16-pos chunk); wave = 16-co M-tile (8 waves = 128 co).
//  - Whi A-frags persistent in VGPRs (36 k-tiles x 4 VGPR = 144), loaded once
//    from pre-repacked fragment array; Wlo streamed from L2 (address-stable).
//  - K order dk-major (k = dk*128 + ci) -> B-frag = one aligned ds_read_b128
//    from [pos][ci] fp16 planes (row stride 68 u32 -> 2-way conflicts = free).
//  - Sync: per-(b,row,chunk) flags; consumer waits only on 2 neighbor chunks
//    (halo +-4 < 16). H: 208 blocks, W: 80 -> co-resident, no deadlock.

#define B_ 16
#define C_ 128
#define H_ 72
#define W_ 200
#define KW 9
#define NTOT (B_ * C_ * H_ * W_)

using f16x8 = _Float16 __attribute__((ext_vector_type(8)));
using f32x4 = float __attribute__((ext_vector_type(4)));

__device__ __forceinline__ unsigned pack_h2(_Float16 lo, _Float16 hi) {
  unsigned short a = __builtin_bit_cast(unsigned short, lo);
  unsigned short b = __builtin_bit_cast(unsigned short, hi);
  return (unsigned)a | ((unsigned)b << 16);
}

// ---------------- copy x -> out ----------------
__global__ void copy_f4(const float4* __restrict__ src, float4* __restrict__ dst, int n4) {
  int i = blockIdx.x * blockDim.x + threadIdx.x;
  const int stride = gridDim.x * blockDim.x;
  for (; i < n4; i += stride) dst[i] = src[i];
}

// ---------------- transpose last two dims ----------------
template <int SH, int SW>
__global__ void transpose_hw(const float* __restrict__ src, float* __restrict__ dst) {
  __shared__ float t[32][33];
  const size_t base = (size_t)blockIdx.z * SH * SW;
  const int x = blockIdx.x * 32 + threadIdx.x;
#pragma unroll
  for (int j = 0; j < 4; ++j) {
    const int y = blockIdx.y * 32 + threadIdx.y + j * 8;
    if (y < SH && x < SW) t[threadIdx.y + j * 8][threadIdx.x] = src[base + (size_t)y * SW + x];
  }
  __syncthreads();
  const int x2 = blockIdx.y * 32 + threadIdx.x;
#pragma unroll
  for (int j = 0; j < 4; ++j) {
    const int y2 = blockIdx.x * 32 + threadIdx.y + j * 8;
    if (y2 < SW && x2 < SH) dst[base + (size_t)y2 * SH + x2] = t[threadIdx.x][threadIdx.y + j * 8];
  }
}

// ---------------- weight repack: wgt[co][ci][dk] -> MFMA A-frag order ----------------
// frag index: [cot(8)][t(36)][lane(64)] f16x8; lane: m=lane&15 (co), q=lane>>4;
// element j <-> k = t*32 + q*8 + j, k = dk*128 + ci (dk = t>>2, ci = (t&3)*32 + q*8 + j)
__global__ void repack_w(const float* __restrict__ wgt, f16x8* __restrict__ whi,
                         f16x8* __restrict__ wlo) {
  const int blk = blockIdx.x;  // cot*36 + t
  const int cot = blk / 36, t = blk % 36;
  const int lane = threadIdx.x;
  const int n = lane & 15, q = lane >> 4;
  const int co = cot * 16 + n, dk = t >> 2, ci0 = (t & 3) * 32 + q * 8;
  f16x8 h, l;
#pragma unroll
  for (int j = 0; j < 8; ++j) {
    const float w = wgt[((size_t)co * C_ + ci0 + j) * KW + dk];
    const _Float16 hh = (_Float16)w;
    h[j] = hh;
    l[j] = (_Float16)(w - (float)hh);
  }
  whi[(size_t)blk * 64 + lane] = h;
  wlo[(size_t)blk * 64 + lane] = l;
}

// ---------------- MFMA scan pass ----------------
// data[b][c][RDIM][WDIM]; scan RDIM rows; conv (K=9,pad4) over contiguous WDIM.
// grid = 16*NCH blocks: b = bx&15, chunk jc = bx>>4 (16 positions).
template <int RDIM, int WDIM, int NCH>
__global__ __launch_bounds__(512, 1) void pass_mfma(float* __restrict__ data,
                                                    const f16x8* __restrict__ whi,
                                                    const f16x8* __restrict__ wlo,
                                                    unsigned* flags, const int dir) {
  constexpr int RW = RDIM * WDIM;
  __shared__ float win[128 * 25];  // natural [ci][wi(24)+1pad]
  __shared__ unsigned fh[24 * 68]; // [wi][ci-pair(64)] packed fp16 hi, stride 68
  __shared__ unsigned fl[24 * 68]; // lo plane

  const int tid = threadIdx.x;
  const int wave = tid >> 6, lane = tid & 63;
  const int n = lane & 15, q = lane >> 4;
  const int b = blockIdx.x & 15, jc = blockIdx.x >> 4;
  const int pos_base = jc * 16;
  const size_t bbase = (size_t)b * C_ * RW;

  // persistent A-frags (Whi) in VGPRs: 36 x 4 VGPR
  f16x8 ahi[36];
#pragma unroll
  for (int t = 0; t < 36; ++t) ahi[t] = whi[(size_t)(wave * 36 + t) * 64 + lane];
  const f16x8* wloL = wlo + (size_t)wave * 36 * 64 + lane;

  for (int s = 1; s < RDIM; ++s) {
    const int r = (dir > 0) ? s : (RDIM - 1 - s);
    const int rp = r - dir;  // producer row

    if (s > 1 && tid < 2) {
      const int jn = jc + (tid ? 1 : -1);
      if (jn >= 0 && jn < NCH) {
        unsigned* f = &flags[((size_t)b * RDIM + rp) * NCH + jn];
        while (__hip_atomic_load(f, __ATOMIC_RELAXED, __HIP_MEMORY_SCOPE_AGENT) == 0u)
          __builtin_amdgcn_s_sleep(1);
        (void)__hip_atomic_load(f, __ATOMIC_ACQUIRE, __HIP_MEMORY_SCOPE_AGENT);
      }
    }
    __syncthreads();

    // preload current row r (written only by this block) to hide RMW latency
    const int pos = pos_base + n;
    float cur[4];
#pragma unroll
    for (int reg = 0; reg < 4; ++reg) {
      const int co = wave * 16 + q * 4 + reg;
      cur[reg] = (pos < WDIM) ? data[bbase + (size_t)co * RW + (size_t)r * WDIM + pos] : 0.f;
    }

    // phase 1: global row rp window [pos_base-4, pos_base+20) -> win (coalesced runs)
#pragma unroll
    for (int i = 0; i < 6; ++i) {
      const int idx = tid + 512 * i;  // 3072 = 128ci * 24wi
      const int ci = idx / 24, wi = idx - ci * 24;
      const int p = pos_base - 4 + wi;
      float v = 0.f;
      if (p >= 0 && p < WDIM) v = data[bbase + (size_t)ci * RW + (size_t)rp * WDIM + p];
      win[ci * 25 + wi] = v;
    }
    __syncthreads();

    // phase 2: transpose + split fp32 -> fp16 hi/lo planes [wi][ci]
#pragma unroll
    for (int i = 0; i < 3; ++i) {
      const int idx = tid + 512 * i;  // 1536 = 24wi * 64 ci-pairs
      const int wi = idx >> 6, c2 = idx & 63;
      const float x0 = win[(2 * c2) * 25 + wi];
      const float x1 = win[(2 * c2 + 1) * 25 + wi];
      const _Float16 h0 = (_Float16)x0, h1 = (_Float16)x1;
      const _Float16 l0 = (_Float16)(x0 - (float)h0), l1 = (_Float16)(x1 - (float)h1);
      fh[wi * 68 + c2] = pack_h2(h0, h1);
      fl[wi * 68 + c2] = pack_h2(l0, l1);
    }
    __syncthreads();

    // MFMA: D[co16 x pos16], K = 1152 (36 k-tiles), 3-term split
    f32x4 aA = {0.f, 0.f, 0.f, 0.f}, aB = {0.f, 0.f, 0.f, 0.f}, aC = {0.f, 0.f, 0.f, 0.f};
#pragma unroll
    for (int t = 0; t < 36; ++t) {
      const int dk = t >> 2;
      const int off = (n + dk) * 68 + (t & 3) * 16 + q * 4;  // u32 idx, 16B-aligned
      const f16x8 bh = *(const f16x8*)&fh[off];
      const f16x8 bl = *(const f16x8*)&fl[off];
      const f16x8 al = wloL[(size_t)t * 64];
      aA = __builtin_amdgcn_mfma_f32_16x16x32_f16(ahi[t], bh, aA, 0, 0, 0);
      aB = __builtin_amdgcn_mfma_f32_16x16x32_f16(ahi[t], bl, aB, 0, 0, 0);
      aC = __builtin_amdgcn_mfma_f32_16x16x32_f16(al, bh, aC, 0, 0, 0);
    }

    // epilogue: C/D layout col=lane&15 (pos), row=q*4+reg (co-within-tile)
    if (pos < WDIM) {
#pragma unroll
      for (int reg = 0; reg < 4; ++reg) {
        const int co = wave * 16 + q * 4 + reg;
        const float v = aA[reg] + aB[reg] + aC[reg];
        data[bbase + (size_t)co * RW + (size_t)r * WDIM + pos] = cur[reg] + fmaxf(v, 0.f);
      }
    }
    __syncthreads();  // vmcnt(0) drain before s_barrier -> stores visible
    if (tid == 0)
      __hip_atomic_store(&flags[((size_t)b * RDIM + r) * NCH + jc], 1u, __ATOMIC_RELEASE,
                         __HIP_MEMORY_SCOPE_AGENT);
  }
}

extern "C" void kernel_launch(void* const* d_in, const int* in_sizes, int n_in, void* d_out,
                              int out_size, void* d_ws, size_t ws_size, hipStream_t stream) {
  const float* x = (const float*)d_in[0];
  const float* w_down = (const float*)d_in[1];
  const float* w_up = (const float*)d_in[2];
  const float* w_right = (const float*)d_in[3];
  const float* w_left = (const float*)d_in[4];
  float* out = (float*)d_out;

  // ---- ws layout ----
  // [0, 256K):        flags (memset 0)
  // [256K, 256K+8*294912): weight frag planes (hi,lo) x 4 passes
  // [2,621,440, ...): transpose scratch T if it fits, else reuse d_in[0]
  unsigned* flags = (unsigned*)d_ws;
  unsigned* f_down = flags;                      // 72*13*16 = 14976
  unsigned* f_up = f_down + H_ * 13 * B_;        // 14976
  unsigned* f_right = f_up + H_ * 13 * B_;       // 200*5*16 = 16000
  unsigned* f_left = f_right + W_ * 5 * B_;      // 16000
  hipMemsetAsync(d_ws, 0, 262144, stream);

  const size_t PLANE = (size_t)8 * 36 * 64;  // f16x8 elements per plane = 294912 B
  f16x8* wf = (f16x8*)((char*)d_ws + 262144);
  f16x8* whi_d = wf + 0 * PLANE;
  f16x8* wlo_d = wf + 1 * PLANE;
  f16x8* whi_u = wf + 2 * PLANE;
  f16x8* wlo_u = wf + 3 * PLANE;
  f16x8* whi_r = wf + 4 * PLANE;
  f16x8* wlo_r = wf + 5 * PLANE;
  f16x8* whi_l = wf + 6 * PLANE;
  f16x8* wlo_l = wf + 7 * PLANE;

  const size_t toff = 262144 + 8 * PLANE * sizeof(f16x8);
  const size_t tbytes = (size_t)NTOT * sizeof(float);
  float* T = (ws_size >= toff + tbytes) ? (float*)((char*)d_ws + toff) : (float*)d_in[0];

  // weight repack (one-time per launch)
  repack_w<<<288, 64, 0, stream>>>(w_down, whi_d, wlo_d);
  repack_w<<<288, 64, 0, stream>>>(w_up, whi_u, wlo_u);
  repack_w<<<288, 64, 0, stream>>>(w_right, whi_r, wlo_r);
  repack_w<<<288, 64, 0, stream>>>(w_left, whi_l, wlo_l);

  // out = x
  copy_f4<<<1024, 256, 0, stream>>>((const float4*)x, (float4*)out, NTOT / 4);

  // down/up: scan h (RDIM=72), conv over w (WDIM=200, 13 chunks) -> 208 blocks
  pass_mfma<H_, W_, 13><<<16 * 13, 512, 0, stream>>>(out, whi_d, wlo_d, f_down, +1);
  pass_mfma<H_, W_, 13><<<16 * 13, 512, 0, stream>>>(out, whi_u, wlo_u, f_up, -1);

  // transpose [b,c,h,w] -> [b,c,w,h]
  {
    dim3 g((W_ + 31) / 32, (H_ + 31) / 32, B_ * C_);
    transpose_hw<H_, W_><<<g, dim3(32, 8), 0, stream>>>(out, T);
  }

  // right/left: scan w (RDIM=200), conv over h (WDIM=72, 5 chunks) -> 80 blocks
  pass_mfma<W_, H_, 5><<<16 * 5, 512, 0, stream>>>(T, whi_r, wlo_r, f_right, +1);
  pass_mfma<W_, H_, 5><<<16 * 5, 512, 0, stream>>>(T, whi_l, wlo_l, f_left, -1);

  // transpose back
  {
    dim3 g((H_ + 31) / 32, (W_ + 31) / 32, B_ * C_);
    transpose_hw<W_, H_><<<g, dim3(32, 8), 0, stream>>>(T, out);
  }
}